// Round 11
// baseline (197.623 us; speedup 1.0000x reference)
//
#include <hip/hip_runtime.h>
#include <math.h>

typedef unsigned short ushort_t;
typedef unsigned int uint_t;
typedef __attribute__((ext_vector_type(8))) short short8;
typedef __attribute__((ext_vector_type(4))) float f32x4;

#define NB 4
#define NC 64
#define NH 128
#define NW 128
#define OFFC 32

// ws layout (float units) — total 6,603,136 floats = 26,412,544 B (r2/r4-proven).
//   xt     @ 0         : 4,194,304
//   coefA  @ 4194304   : 2,359,296  uint4/(tap,px): coef f32, idx in low 7 mantissa bits
//   wt_off @ 6553600   : 8,064
//   g_wbh  @ 6561664   : 20,736
//   g_wbl  @ 6582400   : 20,736

__device__ __forceinline__ void async_copy16(void* lds_dst, const void* g_src) {
    __builtin_amdgcn_global_load_lds(
        (const __attribute__((address_space(1))) unsigned int*)g_src,
        (__attribute__((address_space(3))) unsigned int*)lds_dst, 16, 0, 0);
}

__device__ __forceinline__ void split_bf16(float v, ushort_t& h, ushort_t& l) {
    uint_t bb = __float_as_uint(v);
    uint_t rr = bb + 0x7fffu + ((bb >> 16) & 1u);   // RNE for hi (weights path)
    h = (ushort_t)(rr >> 16);
    float hf = __uint_as_float(((uint_t)h) << 16);
    float lof = v - hf;
    l = (ushort_t)(__float_as_uint(lof) >> 16);
}

__global__ __launch_bounds__(256) void prep_weights(
        const float* __restrict__ weight, const float* __restrict__ w_off,
        ushort_t* __restrict__ g_wbh, ushort_t* __restrict__ g_wbl,
        float* __restrict__ wt_off) {
    int idx = blockIdx.x * 256 + threadIdx.x;
    if (idx < 9 * 64 * 72) {
        int k   = idx % 72;
        int o   = (idx / 72) % 64;
        int tap = idx / (72 * 64);
        float v = (k < 64) ? weight[(o * 64 + k) * 9 + tap] : 0.0f;
        ushort_t h, l;
        split_bf16(v, h, l);
        g_wbh[idx] = h;
        g_wbl[idx] = l;
    }
    int idx2 = idx - 9 * 64 * 72;
    if (idx2 >= 0 && idx2 < 32 * 9 * 28) {
        int oc  = idx2 % 28;
        int r   = idx2 / 28;
        int tap = r % 9;
        int ic  = r / 9;
        wt_off[idx2] = (oc < 27) ? w_off[(oc * 32 + ic) * 9 + tap] : 0.0f;
    }
}

// Fused: blocks [0,512) transpose x -> xt; blocks [512,1536) offset conv + coef pack.
// Offset branch: feat window staged in LDS (kills the 72-global-load latency chain);
// wt_off reads guaranteed scalar via readfirstlane(wave-id).
__global__ __launch_bounds__(256) void aux_fused(
        const float* __restrict__ xin, float* __restrict__ xt,
        const float* __restrict__ feat, const float* __restrict__ wt_off,
        const float* __restrict__ b_off, uint_t* __restrict__ coefA) {
    // offset branch: feat_lds 32*200=6400 fl (25,600 B) + red 4*27*64=6912 fl (27,648 B)
    //              = 13,312 fl = 53,248 B -> exactly 3 blocks/CU (159,744 <= 163,840)
    // transpose branch: 64*130 = 8,320 fl
    __shared__ __align__(16) float smem[13312];
    int bid = blockIdx.x;
    int t = threadIdx.x;
    if (bid < 512) {
        float (*lds)[130] = (float (*)[130])smem;
        int b = bid >> 7;
        int y = bid & 127;
        int xx = t & 127;
        int c0 = t >> 7;
#pragma unroll
        for (int it = 0; it < 32; ++it) {
            int c = it * 2 + c0;
            lds[c][xx] = xin[((b * 64 + c) * 128 + y) * 128 + xx];
        }
        __syncthreads();
#pragma unroll
        for (int it = 0; it < 32; ++it) {
            int flat = it * 256 + t;
            int c  = flat & 63;
            int x2 = flat >> 6;
            xt[((b * 128 + y) * 128 + x2) * 64 + c] = lds[c][x2];
        }
        return;
    }
    // ---- offset conv branch ----
    float* feat_lds = smem;                                   // [ic][row*66+pos], stride 200
    float (*red)[27][64] = (float (*)[27][64])(smem + 6400);
    int wvu = __builtin_amdgcn_readfirstlane(t >> 6);         // uniform wave id 0..3
    int lane = t & 63;
    int pix0 = (bid - 512) * 64;
    int b  = pix0 >> 14;
    int y  = (pix0 >> 7) & 127;
    int x0 = pix0 & 127;                                      // 0 or 64
    const float* fb = feat + (size_t)b * (OFFC * NH * NW);
    // stage [32 ic][3 rows][66 px] window, zero-padded OOB; wave wvu -> j = wvu*24+k
#pragma unroll
    for (int k = 0; k < 24; ++k) {
        int j = wvu * 24 + k;
        int ic = j / 3, row = j - ic * 3;
        int gy = y - 1 + row;
        bool vy = (gy >= 0) && (gy < NH);
        int gx = x0 - 1 + lane;
        float v0 = (vy && gx >= 0 && gx < NW) ? fb[(ic * NH + gy) * NW + gx] : 0.0f;
        feat_lds[ic * 200 + row * 66 + lane] = v0;
        if (lane < 2) {
            int gx2 = x0 + 63 + lane;
            float v1 = (vy && gx2 < NW) ? fb[(ic * NH + gy) * NW + gx2] : 0.0f;
            feat_lds[ic * 200 + row * 66 + 64 + lane] = v1;
        }
    }
    __syncthreads();
    float acc[27];
#pragma unroll
    for (int o = 0; o < 27; ++o) acc[o] = 0.0f;
#pragma unroll
    for (int i = 0; i < 8; ++i) {
        int ic = wvu * 8 + i;
        float v[9];
#pragma unroll
        for (int kh = 0; kh < 3; ++kh)
#pragma unroll
            for (int kw = 0; kw < 3; ++kw)
                v[kh * 3 + kw] = feat_lds[ic * 200 + kh * 66 + lane + kw];
#pragma unroll
        for (int tap = 0; tap < 9; ++tap)
#pragma unroll
            for (int o = 0; o < 27; ++o)
                acc[o] = fmaf(v[tap], wt_off[(ic * 9 + tap) * 28 + o], acc[o]);
    }
#pragma unroll
    for (int o = 0; o < 27; ++o) red[wvu][o][lane] = acc[o];
    __syncthreads();
    for (int tp = wvu; tp < 9; tp += 4) {
        int pix = pix0 + lane;
        float dy = red[0][2 * tp][lane] + red[1][2 * tp][lane]
                 + red[2][2 * tp][lane] + red[3][2 * tp][lane] + b_off[2 * tp];
        float dx = red[0][2 * tp + 1][lane] + red[1][2 * tp + 1][lane]
                 + red[2][2 * tp + 1][lane] + red[3][2 * tp + 1][lane] + b_off[2 * tp + 1];
        float mv = red[0][18 + tp][lane] + red[1][18 + tp][lane]
                 + red[2][18 + tp][lane] + red[3][18 + tp][lane] + b_off[18 + tp];
        float mm = 1.0f / (1.0f + __expf(-mv));
        float py  = (float)(y - 1 + tp / 3) + dy;
        float pxf = (float)((pix & 127) - 1 + tp % 3) + dx;
        float y0f = floorf(py), x0f = floorf(pxf);
        float wy = py - y0f, wx = pxf - x0f;
        int iy0 = (int)y0f, ix0 = (int)x0f;
        int iy1 = iy0 + 1, ix1 = ix0 + 1;
        float vy0 = (iy0 >= 0 && iy0 < NH) ? 1.0f : 0.0f;
        float vy1 = (iy1 >= 0 && iy1 < NH) ? 1.0f : 0.0f;
        float vx0 = (ix0 >= 0 && ix0 < NW) ? 1.0f : 0.0f;
        float vx1 = (ix1 >= 0 && ix1 < NW) ? 1.0f : 0.0f;
        int iy0c = min(max(iy0, 0), NH - 1), iy1c = min(max(iy1, 0), NH - 1);
        int ix0c = min(max(ix0, 0), NW - 1), ix1c = min(max(ix1, 0), NW - 1);
        float c00 = (1.0f - wy) * (1.0f - wx) * vy0 * vx0 * mm;
        float c01 = (1.0f - wy) * wx * vy0 * vx1 * mm;
        float c10 = wy * (1.0f - wx) * vy1 * vx0 * mm;
        float c11 = wy * wx * vy1 * vx1 * mm;
        // coefs >= 0; clamped indices in low 7 mantissa bits (<=127 ulp perturbation).
        uint_t u00 = (__float_as_uint(c00) & ~127u) | (uint_t)iy0c;
        uint_t u01 = (__float_as_uint(c01) & ~127u) | (uint_t)iy1c;
        uint_t u10 = (__float_as_uint(c10) & ~127u) | (uint_t)ix0c;
        uint_t u11 = (__float_as_uint(c11) & ~127u) | (uint_t)ix1c;
        *(uint4*)&coefA[((size_t)tp * 65536 + pix) * 4] = make_uint4(u00, u01, u10, u11);
    }
}

// Fused sample + bf16-split MFMA GEMM. Block = 8 waves, one (b,y) row (128 px).
// Sampling scalarized: per (wave,tap) ONE coalesced coef load (lane l = word l of
// 16px x 4 corners), v_readlane -> SGPR unpack/addressing (SALU), saddr gathers.
__global__ __launch_bounds__(512, 4) void deform_main(
        const float* __restrict__ xt, const uint_t* __restrict__ coefA,
        const ushort_t* __restrict__ g_wbh, const ushort_t* __restrict__ g_wbl,
        const float* __restrict__ bias, float* __restrict__ out) {
    __shared__ __align__(16) ushort_t s_hi[128][72];       // 18,432 B
    __shared__ __align__(16) ushort_t s_lo[128][72];       // 18,432 B
    __shared__ __align__(16) ushort_t wb[2][2][64][72];    // 36,864 B

    int lane = threadIdx.x & 63;
    int wu = __builtin_amdgcn_readfirstlane(threadIdx.x >> 6);  // uniform wave id
    int col = lane & 15;
    int kgrp = lane >> 4;
    int blk = (blockIdx.x & 7) * 64 + (blockIdx.x >> 3);   // XCD swizzle (512=8x64)
    int b = blk >> 7, y = blk & 127;
    int pix0 = blk * 128;
    const float* xb = xt + (size_t)b * (NH * NW * NC);

    f32x4 acc[4];
#pragma unroll
    for (int n = 0; n < 4; ++n) {
        float bv = bias[n * 16 + col];
        acc[n] = (f32x4){bv, bv, bv, bv};
    }

    auto prefetchW = [&](int tap, int bi) {
        for (int j = wu; j < 18; j += 8) {
            int hsel = (j < 9) ? 0 : 1;
            int j2 = (j < 9) ? j : j - 9;
            const ushort_t* src = (hsel ? g_wbl : g_wbh) + tap * 4608 + j2 * 512 + lane * 8;
            ushort_t* dst = &wb[bi][hsel][0][0] + j2 * 512;
            async_copy16(dst, src);
        }
    };

    prefetchW(0, 0);
    __syncthreads();

    for (int t = 0; t < 9; ++t) {
        // ---- sampling: 16 px per wave; coef words for all 16 px in one load ----
        uint_t cw = coefA[((size_t)t * 65536 + pix0) * 4 + wu * 64 + lane];
#pragma unroll
        for (int p = 0; p < 16; ++p) {
            uint_t u00 = (uint_t)__builtin_amdgcn_readlane((int)cw, 4 * p + 0);
            uint_t u01 = (uint_t)__builtin_amdgcn_readlane((int)cw, 4 * p + 1);
            uint_t u10 = (uint_t)__builtin_amdgcn_readlane((int)cw, 4 * p + 2);
            uint_t u11 = (uint_t)__builtin_amdgcn_readlane((int)cw, 4 * p + 3);
            float c00 = __uint_as_float(u00 & ~127u);
            float c01 = __uint_as_float(u01 & ~127u);
            float c10 = __uint_as_float(u10 & ~127u);
            float c11 = __uint_as_float(u11 & ~127u);
            const float* r0 = xb + ((u00 & 127u) << 13);   // iy0c row base
            const float* r1 = xb + ((u01 & 127u) << 13);   // iy1c row base
            uint_t q0 = (u10 & 127u) << 6;                 // ix0c * 64
            uint_t q1 = (u11 & 127u) << 6;                 // ix1c * 64
            const float* p00 = r0 + q0;
            const float* p01 = r0 + q1;
            const float* p10 = r1 + q0;
            const float* p11 = r1 + q1;
            float v00 = p00[lane];
            float v01 = p01[lane];
            float v10 = p10[lane];
            float v11 = p11[lane];
            float s = c00 * v00;
            s = fmaf(c01, v01, s);
            s = fmaf(c10, v10, s);
            s = fmaf(c11, v11, s);
            // truncate-split: v = hi + lo exactly; lo trunc to bf16 (err <= 2^-16 |v|)
            uint_t sb = __float_as_uint(s);
            float lof = s - __uint_as_float(sb & 0xffff0000u);
            int rowi = wu * 16 + p;
            s_hi[rowi][lane] = (ushort_t)(sb >> 16);
            s_lo[rowi][lane] = (ushort_t)(__float_as_uint(lof) >> 16);
        }
        if (t < 8) prefetchW(t + 1, (t + 1) & 1);
        __syncthreads();   // s tiles + wb[t] ready (prefetch t+1 in flight ok)

        // ---- GEMM: m-tile = wu, 4 n-tiles, 6 k-steps (hh,hl,lh) ----
        {
            int bi = t & 1;
            short8 ah[2], al[2];
#pragma unroll
            for (int ks = 0; ks < 2; ++ks) {
                int row = wu * 16 + col;
                ah[ks] = *(const short8*)&s_hi[row][ks * 32 + kgrp * 8];
                al[ks] = *(const short8*)&s_lo[row][ks * 32 + kgrp * 8];
            }
#pragma unroll
            for (int h = 0; h < 2; ++h) {
                short8 bh[2][2], bl[2][2];
#pragma unroll
                for (int n2 = 0; n2 < 2; ++n2)
#pragma unroll
                    for (int ks = 0; ks < 2; ++ks) {
                        int o = (h * 2 + n2) * 16 + col;
                        bh[n2][ks] = *(const short8*)&wb[bi][0][o][ks * 32 + kgrp * 8];
                        bl[n2][ks] = *(const short8*)&wb[bi][1][o][ks * 32 + kgrp * 8];
                    }
#pragma unroll
                for (int n2 = 0; n2 < 2; ++n2) {
                    int n = h * 2 + n2;
                    acc[n] = __builtin_amdgcn_mfma_f32_16x16x32_bf16(ah[0], bh[n2][0], acc[n], 0, 0, 0);
                    acc[n] = __builtin_amdgcn_mfma_f32_16x16x32_bf16(ah[1], bh[n2][1], acc[n], 0, 0, 0);
                    acc[n] = __builtin_amdgcn_mfma_f32_16x16x32_bf16(ah[0], bl[n2][0], acc[n], 0, 0, 0);
                    acc[n] = __builtin_amdgcn_mfma_f32_16x16x32_bf16(ah[1], bl[n2][1], acc[n], 0, 0, 0);
                    acc[n] = __builtin_amdgcn_mfma_f32_16x16x32_bf16(al[0], bh[n2][0], acc[n], 0, 0, 0);
                    acc[n] = __builtin_amdgcn_mfma_f32_16x16x32_bf16(al[1], bh[n2][1], acc[n], 0, 0, 0);
                }
            }
        }
        __syncthreads();   // GEMM done before next tap overwrites s / wb buf
    }

#pragma unroll
    for (int n = 0; n < 4; ++n) {
        int o = n * 16 + col;
        int x = wu * 16 + kgrp * 4;
        float* dst = out + (((size_t)(b * 64 + o)) * 128 + y) * 128 + x;
        *(f32x4*)dst = acc[n];
    }
}

extern "C" void kernel_launch(void* const* d_in, const int* in_sizes, int n_in,
                              void* d_out, int out_size, void* d_ws, size_t ws_size,
                              hipStream_t stream) {
    const float* x        = (const float*)d_in[0];
    const float* off_feat = (const float*)d_in[1];
    const float* w_off    = (const float*)d_in[2];
    const float* b_off    = (const float*)d_in[3];
    const float* weight   = (const float*)d_in[4];
    const float* bias     = (const float*)d_in[5];
    float* out = (float*)d_out;

    float* ws      = (float*)d_ws;
    float* xt      = ws;                          // 4,194,304
    uint_t* coefA  = (uint_t*)(ws + 4194304);     // 2,359,296
    float* wt_off  = ws + 6553600;                // 8,064
    ushort_t* g_wbh = (ushort_t*)(ws + 6561664);  // 41,472 ushorts
    ushort_t* g_wbl = (ushort_t*)(ws + 6582400);  // 41,472 ushorts

    prep_weights<<<194, 256, 0, stream>>>(weight, w_off, g_wbh, g_wbl, wt_off);
    aux_fused<<<1536, 256, 0, stream>>>(x, xt, off_feat, wt_off, b_off, coefA);
    deform_main<<<512, 512, 0, stream>>>(xt, coefA, g_wbh, g_wbl, bias, out);
}